// Round 1
// baseline (994.352 us; speedup 1.0000x reference)
//
#include <hip/hip_runtime.h>
#include <hip/hip_bf16.h>
#include <math.h>

// ---------------------------------------------------------------------------
// TransformerBlock: x:[2,2048,2048] fp32
//   ln1 -> qkv gemm -> causal flash attn -> proj(+bo)+res -> ln2
//   -> ffn1(+b1, buggy-gelu) -> ffn2(+b2)+res -> out fp32
// All GEMMs bf16 MFMA 16x16x32, fp32 accum. Softmax/LN in fp32.
// ---------------------------------------------------------------------------

typedef short bf16x8 __attribute__((ext_vector_type(8)));
typedef float f32x4 __attribute__((ext_vector_type(4)));
typedef short short4v __attribute__((ext_vector_type(4)));

#define MFMA16x32(a, b, c) __builtin_amdgcn_mfma_f32_16x16x32_bf16((a), (b), (c), 0, 0, 0)

__device__ __forceinline__ short f2bs(float f) {
    // fp32 -> bf16 round-to-nearest-even
    unsigned u = __builtin_bit_cast(unsigned, f);
    unsigned r = (u + 0x7FFFu + ((u >> 16) & 1u)) >> 16;
    return (short)(unsigned short)r;
}

// ---------- transpose fp32 (R x C) -> bf16 (C x R) ----------
__global__ __launch_bounds__(256) void transpose_kernel(const float* __restrict__ in,
                                                        short* __restrict__ out,
                                                        int R, int C) {
    __shared__ float tile[32][33];
    const int tx = threadIdx.x & 31;
    const int ty = threadIdx.x >> 5;  // 0..7
    const int c0 = blockIdx.x * 32;
    const int r0 = blockIdx.y * 32;
#pragma unroll
    for (int i = 0; i < 4; ++i) {
        int r = ty + i * 8;
        tile[r][tx] = in[(size_t)(r0 + r) * C + c0 + tx];
    }
    __syncthreads();
#pragma unroll
    for (int i = 0; i < 4; ++i) {
        int r = ty + i * 8;
        out[(size_t)(c0 + r) * R + r0 + tx] = f2bs(tile[tx][r]);
    }
}

// ---------- layernorm fp32 row (D=2048) -> bf16 row ----------
__global__ __launch_bounds__(256) void ln_kernel(const float* __restrict__ x,
                                                 const float* __restrict__ sc,
                                                 const float* __restrict__ sh,
                                                 short* __restrict__ out) {
    const int D = 2048;
    const int row = blockIdx.x;
    const int tid = threadIdx.x;
    __shared__ float red[4];
    const float4* xr = (const float4*)(x + (size_t)row * D);
    float4 v0 = xr[tid];
    float4 v1 = xr[tid + 256];
    float vals0[4] = {v0.x, v0.y, v0.z, v0.w};
    float vals1[4] = {v1.x, v1.y, v1.z, v1.w};

    float s = vals0[0] + vals0[1] + vals0[2] + vals0[3] + vals1[0] + vals1[1] + vals1[2] + vals1[3];
#pragma unroll
    for (int off = 32; off; off >>= 1) s += __shfl_xor(s, off);
    if ((tid & 63) == 0) red[tid >> 6] = s;
    __syncthreads();
    float mean = (red[0] + red[1] + red[2] + red[3]) * (1.0f / 2048.0f);
    __syncthreads();

    float q = 0.0f;
#pragma unroll
    for (int j = 0; j < 4; ++j) {
        float t0 = vals0[j] - mean;
        float t1 = vals1[j] - mean;
        q += t0 * t0 + t1 * t1;
    }
#pragma unroll
    for (int off = 32; off; off >>= 1) q += __shfl_xor(q, off);
    if ((tid & 63) == 0) red[tid >> 6] = q;
    __syncthreads();
    float var = (red[0] + red[1] + red[2] + red[3]) * (1.0f / 2048.0f);
    float inv = rsqrtf(var + 1e-5f);

    const int c0 = tid * 4;
    const int c1 = (tid + 256) * 4;
    short4v o0, o1;
#pragma unroll
    for (int j = 0; j < 4; ++j) {
        o0[j] = f2bs(sc[c0 + j] * ((vals0[j] - mean) * inv) + sh[c0 + j]);
        o1[j] = f2bs(sc[c1 + j] * ((vals1[j] - mean) * inv) + sh[c1 + j]);
    }
    *(short4v*)(out + (size_t)row * D + c0) = o0;
    *(short4v*)(out + (size_t)row * D + c1) = o1;
}

// ---------- bf16 GEMM: C[M,N] = A[M,K] @ Bt[N,K]^T (+epilogue) ----------
// EPI 0: store bf16
// EPI 1: store fp32 = acc + bias[col] + res[row*N+col]
// EPI 2: store bf16 = buggy_gelu(acc + bias[col])
template <int EPI>
__global__ __launch_bounds__(256) void gemm_bf16(const short* __restrict__ A,
                                                 const short* __restrict__ Bt,
                                                 int M, int N, int K,
                                                 void* __restrict__ Cout,
                                                 const float* __restrict__ bias,
                                                 const float* __restrict__ res,
                                                 float gconst) {
    constexpr int LDP = 40;  // 32 + 8 pad (16B) -> 80B row stride, conflict-free-ish, 16B aligned
    __shared__ short As[128 * LDP];
    __shared__ short Bs[128 * LDP];
    const int tid = threadIdx.x;
    const int lane = tid & 63;
    const int wid = tid >> 6;
    const int wm = wid >> 1, wn = wid & 1;
    const int l15 = lane & 15, grp = lane >> 4;
    const long m0 = (long)blockIdx.y * 128, n0 = (long)blockIdx.x * 128;

    const int ar0 = tid >> 2;          // rows 0..63
    const int ar1 = ar0 + 64;          // rows 64..127
    const int ac0 = (tid & 3) * 8;     // k-chunk within 32

    const short* Ab = A + m0 * K;
    const short* Bb = Bt + n0 * K;

    f32x4 zero = {0.f, 0.f, 0.f, 0.f};
    f32x4 acc[4][4];
#pragma unroll
    for (int i = 0; i < 4; i++)
#pragma unroll
        for (int j = 0; j < 4; j++) acc[i][j] = zero;

    for (int k0 = 0; k0 < K; k0 += 32) {
        bf16x8 ra0 = *(const bf16x8*)(Ab + (size_t)ar0 * K + k0 + ac0);
        bf16x8 ra1 = *(const bf16x8*)(Ab + (size_t)ar1 * K + k0 + ac0);
        bf16x8 rb0 = *(const bf16x8*)(Bb + (size_t)ar0 * K + k0 + ac0);
        bf16x8 rb1 = *(const bf16x8*)(Bb + (size_t)ar1 * K + k0 + ac0);
        __syncthreads();
        *(bf16x8*)(As + ar0 * LDP + ac0) = ra0;
        *(bf16x8*)(As + ar1 * LDP + ac0) = ra1;
        *(bf16x8*)(Bs + ar0 * LDP + ac0) = rb0;
        *(bf16x8*)(Bs + ar1 * LDP + ac0) = rb1;
        __syncthreads();
        bf16x8 af[4], bfr[4];
#pragma unroll
        for (int m = 0; m < 4; m++)
            af[m] = *(const bf16x8*)(As + (wm * 64 + m * 16 + l15) * LDP + grp * 8);
#pragma unroll
        for (int n = 0; n < 4; n++)
            bfr[n] = *(const bf16x8*)(Bs + (wn * 64 + n * 16 + l15) * LDP + grp * 8);
#pragma unroll
        for (int m = 0; m < 4; m++)
#pragma unroll
            for (int n = 0; n < 4; n++)
                acc[m][n] = MFMA16x32(af[m], bfr[n], acc[m][n]);
    }

#pragma unroll
    for (int m = 0; m < 4; m++) {
        long gr = m0 + wm * 64 + m * 16 + grp * 4;
#pragma unroll
        for (int n = 0; n < 4; n++) {
            long gcol = n0 + wn * 64 + n * 16 + l15;
#pragma unroll
            for (int r = 0; r < 4; r++) {
                float vv = acc[m][n][r];
                long idx = (gr + r) * N + gcol;
                if (EPI == 0) {
                    ((short*)Cout)[idx] = f2bs(vv);
                } else if (EPI == 1) {
                    ((float*)Cout)[idx] = vv + bias[gcol] + res[idx];
                } else {
                    float t = vv + bias[gcol];
                    float g = 0.5f * t * (1.0f + gconst * (t + 0.044715f * t * t * t));
                    ((short*)Cout)[idx] = f2bs(g);
                }
            }
        }
    }
}

// ---------- causal flash attention: 1 wave per 16 q-rows ----------
// q/k/v interleaved rows of stride LD (=6144); per-head slice of 128 cols.
__global__ __launch_bounds__(64) void flash_kernel(const short* __restrict__ qp,
                                                   const short* __restrict__ kp,
                                                   const short* __restrict__ vp,
                                                   int LD,
                                                   short* __restrict__ ctx) {
    const int S = 2048, D = 2048, HD = 128;
    const int lane = threadIdx.x;
    const int l15 = lane & 15, grp = lane >> 4;
    const int bid = blockIdx.x;
    const int qt = bid & 127;          // S/16
    const int h = (bid >> 7) & 15;
    const int b = bid >> 11;
    const int q0 = qt * 16;
    const float scale = 0.08838834764831845f;  // 1/sqrt(128)
    const float NEGINF = -__builtin_inff();

    bf16x8 aq[4];
    const short* qrow = qp + (size_t)(b * S + q0 + l15) * LD + h * HD;
#pragma unroll
    for (int kc = 0; kc < 4; kc++) aq[kc] = *(const bf16x8*)(qrow + kc * 32 + grp * 8);

    float m_[4], l_[4];
    f32x4 o[8];
    f32x4 zero = {0.f, 0.f, 0.f, 0.f};
#pragma unroll
    for (int r = 0; r < 4; r++) { m_[r] = NEGINF; l_[r] = 0.f; }
#pragma unroll
    for (int n = 0; n < 8; n++) o[n] = zero;

    __shared__ short plds[16 * 32];
    const int ntiles = (q0 + 47) >> 5;
    for (int kt = 0; kt < ntiles; ++kt) {
        const int k0 = kt * 32;
        f32x4 s0 = zero, s1 = zero;
        const short* kr0 = kp + (size_t)(b * S + k0 + l15) * LD + h * HD;
        const short* kr1 = kr0 + (size_t)16 * LD;
#pragma unroll
        for (int kc = 0; kc < 4; kc++) {
            bf16x8 kb0 = *(const bf16x8*)(kr0 + kc * 32 + grp * 8);
            bf16x8 kb1 = *(const bf16x8*)(kr1 + kc * 32 + grp * 8);
            s0 = MFMA16x32(aq[kc], kb0, s0);
            s1 = MFMA16x32(aq[kc], kb1, s1);
        }
        const bool domask = (k0 + 31 > q0);
        float p0[4], p1[4], al[4];
#pragma unroll
        for (int r = 0; r < 4; r++) {
            float a = s0[r] * scale;
            float c = s1[r] * scale;
            if (domask) {
                int qg = q0 + grp * 4 + r;
                if (k0 + l15 > qg) a = NEGINF;
                if (k0 + 16 + l15 > qg) c = NEGINF;
            }
            float mx = fmaxf(a, c);
            mx = fmaxf(mx, __shfl_xor(mx, 1));
            mx = fmaxf(mx, __shfl_xor(mx, 2));
            mx = fmaxf(mx, __shfl_xor(mx, 4));
            mx = fmaxf(mx, __shfl_xor(mx, 8));
            float mn = fmaxf(m_[r], mx);
            al[r] = __expf(m_[r] - mn);
            a = __expf(a - mn);
            c = __expf(c - mn);
            float rs = a + c;
            rs += __shfl_xor(rs, 1);
            rs += __shfl_xor(rs, 2);
            rs += __shfl_xor(rs, 4);
            rs += __shfl_xor(rs, 8);
            l_[r] = l_[r] * al[r] + rs;
            m_[r] = mn;
            p0[r] = a;
            p1[r] = c;
        }
#pragma unroll
        for (int n = 0; n < 8; n++) {
            f32x4 t = o[n];
            t[0] *= al[0]; t[1] *= al[1]; t[2] *= al[2]; t[3] *= al[3];
            o[n] = t;
        }
        __syncthreads();  // protect plds vs previous iteration's reads
#pragma unroll
        for (int r = 0; r < 4; r++) {
            plds[(grp * 4 + r) * 32 + l15] = f2bs(p0[r]);
            plds[(grp * 4 + r) * 32 + 16 + l15] = f2bs(p1[r]);
        }
        __syncthreads();
        bf16x8 pa = *(const bf16x8*)(plds + l15 * 32 + grp * 8);
        const short* vb0 = vp + (size_t)(b * S + k0 + grp * 8) * LD + h * HD + l15;
#pragma unroll
        for (int n = 0; n < 8; n++) {
            bf16x8 vv;
#pragma unroll
            for (int j = 0; j < 8; j++) vv[j] = vb0[(size_t)j * LD + n * 16];
            o[n] = MFMA16x32(pa, vv, o[n]);
        }
    }
    float inv[4];
#pragma unroll
    for (int r = 0; r < 4; r++) inv[r] = 1.0f / l_[r];
    short* cb = ctx + (size_t)(b * S + q0 + grp * 4) * D + h * HD + l15;
#pragma unroll
    for (int n = 0; n < 8; n++)
#pragma unroll
        for (int r = 0; r < 4; r++)
            cb[(size_t)r * D + n * 16] = f2bs(o[n][r] * inv[r]);
}

// ---------------------------------------------------------------------------
extern "C" void kernel_launch(void* const* d_in, const int* in_sizes, int n_in,
                              void* d_out, int out_size, void* d_ws, size_t ws_size,
                              hipStream_t stream) {
    const float* x    = (const float*)d_in[0];
    const float* wq   = (const float*)d_in[1];
    const float* wk   = (const float*)d_in[2];
    const float* wv   = (const float*)d_in[3];
    const float* wo   = (const float*)d_in[4];
    const float* bo   = (const float*)d_in[5];
    const float* w1   = (const float*)d_in[6];
    const float* b1   = (const float*)d_in[7];
    const float* w2   = (const float*)d_in[8];
    const float* b2   = (const float*)d_in[9];
    const float* lnsc = (const float*)d_in[10];
    const float* lnsh = (const float*)d_in[11];

    const int B = 2, S = 2048, D = 2048;
    const int M = B * S;  // 4096

    // workspace carve (all 16B-aligned by construction)
    char* p = (char*)d_ws;
    short* wqkvT = (short*)p; p += (size_t)3 * D * D * 2;   // [6144, 2048] bf16 (wq^T|wk^T|wv^T)
    short* woT   = (short*)p; p += (size_t)D * D * 2;       // [2048, 2048]
    short* w1T   = (short*)p; p += (size_t)4 * D * D * 2;   // [8192, 2048]
    short* w2T   = (short*)p; p += (size_t)4 * D * D * 2;   // [2048, 8192]
    short* lnb   = (short*)p; p += (size_t)M * D * 2;       // [4096, 2048] (ln1, later ln2)
    short* qkvb  = (short*)p;                               // [4096, 6144]
    short* h1    = qkvb;                                    // reuse qkv+ctx (67.1MB) for [4096,8192]
    p += (size_t)M * 3 * D * 2;
    short* ctxb  = (short*)p; p += (size_t)M * D * 2;       // [4096, 2048]
    float* x2    = (float*)p; p += (size_t)M * D * 4;       // [4096, 2048] fp32

    const float gconst = tanhf(sqrtf(2.0f / 3.14159265358979323846f));  // buggy-gelu const

    dim3 blk(256);
    // weight transposes fp32(K,N) -> bf16(N,K)
    transpose_kernel<<<dim3(64, 64), blk, 0, stream>>>(wq, wqkvT, D, D);
    transpose_kernel<<<dim3(64, 64), blk, 0, stream>>>(wk, wqkvT + (size_t)D * D, D, D);
    transpose_kernel<<<dim3(64, 64), blk, 0, stream>>>(wv, wqkvT + (size_t)2 * D * D, D, D);
    transpose_kernel<<<dim3(64, 64), blk, 0, stream>>>(wo, woT, D, D);
    transpose_kernel<<<dim3(256, 64), blk, 0, stream>>>(w1, w1T, D, 4 * D);   // in 2048x8192
    transpose_kernel<<<dim3(64, 256), blk, 0, stream>>>(w2, w2T, 4 * D, D);   // in 8192x2048

    // ln1
    ln_kernel<<<dim3(M), blk, 0, stream>>>(x, lnsc, lnsh, lnb);
    // fused qkv gemm: [4096,2048] @ [2048,6144] -> [4096,6144] bf16
    gemm_bf16<0><<<dim3(3 * D / 128, M / 128), blk, 0, stream>>>(
        lnb, wqkvT, M, 3 * D, D, qkvb, nullptr, nullptr, 0.f);
    // causal flash attention
    flash_kernel<<<dim3(4096), dim3(64), 0, stream>>>(qkvb, qkvb + D, qkvb + 2 * D, 3 * D, ctxb);
    // out-proj + bo + residual(x) -> x2 fp32
    gemm_bf16<1><<<dim3(D / 128, M / 128), blk, 0, stream>>>(
        ctxb, woT, M, D, D, x2, bo, x, 0.f);
    // ln2
    ln_kernel<<<dim3(M), blk, 0, stream>>>(x2, lnsc, lnsh, lnb);
    // ffn1 + b1 + buggy gelu -> h1 bf16
    gemm_bf16<2><<<dim3(4 * D / 128, M / 128), blk, 0, stream>>>(
        lnb, w1T, M, 4 * D, D, h1, b1, nullptr, gconst);
    // ffn2 + b2 + residual(x2) -> out fp32
    gemm_bf16<1><<<dim3(D / 128, M / 128), blk, 0, stream>>>(
        h1, w2T, M, D, 4 * D, (float*)d_out, b2, x2, 0.f);
}

// Round 2
// 939.550 us; speedup vs baseline: 1.0583x; 1.0583x over previous
//
#include <hip/hip_runtime.h>
#include <hip/hip_bf16.h>
#include <math.h>

// ---------------------------------------------------------------------------
// TransformerBlock fwd: ln1 -> qkv gemm -> causal flash attn -> proj+res
//   -> ln2 -> ffn1(buggy-gelu) -> ffn2+res.  bf16 MFMA, fp32 softmax/LN.
// R2: m97-style GEMM (global_load_lds w=16, swizzled LDS), 4-wave flash
//     with LDS-staged K/V^T.
// ---------------------------------------------------------------------------

typedef short bf16x8 __attribute__((ext_vector_type(8)));
typedef float f32x4 __attribute__((ext_vector_type(4)));
typedef short short4v __attribute__((ext_vector_type(4)));

#define MFMA16x32(a, b, c) __builtin_amdgcn_mfma_f32_16x16x32_bf16((a), (b), (c), 0, 0, 0)

__device__ __forceinline__ short f2bs(float f) {
    unsigned u = __builtin_bit_cast(unsigned, f);
    unsigned r = (u + 0x7FFFu + ((u >> 16) & 1u)) >> 16;
    return (short)(unsigned short)r;
}

__device__ __forceinline__ void gload_lds16(const void* g, void* l) {
    __builtin_amdgcn_global_load_lds(
        (const __attribute__((address_space(1))) unsigned int*)g,
        (__attribute__((address_space(3))) unsigned int*)l, 16, 0, 0);
}

// ---------- transpose fp32 (R x C) -> bf16 (C x R) ----------
__global__ __launch_bounds__(256) void transpose_kernel(const float* __restrict__ in,
                                                        short* __restrict__ out,
                                                        int R, int C) {
    __shared__ float tile[32][33];
    const int tx = threadIdx.x & 31;
    const int ty = threadIdx.x >> 5;
    const int c0 = blockIdx.x * 32;
    const int r0 = blockIdx.y * 32;
#pragma unroll
    for (int i = 0; i < 4; ++i) {
        int r = ty + i * 8;
        tile[r][tx] = in[(size_t)(r0 + r) * C + c0 + tx];
    }
    __syncthreads();
#pragma unroll
    for (int i = 0; i < 4; ++i) {
        int r = ty + i * 8;
        out[(size_t)(c0 + r) * R + r0 + tx] = f2bs(tile[tx][r]);
    }
}

// ---------- layernorm fp32 row (D=2048) -> bf16 row ----------
__global__ __launch_bounds__(256) void ln_kernel(const float* __restrict__ x,
                                                 const float* __restrict__ sc,
                                                 const float* __restrict__ sh,
                                                 short* __restrict__ out) {
    const int D = 2048;
    const int row = blockIdx.x;
    const int tid = threadIdx.x;
    __shared__ float red[4];
    const float4* xr = (const float4*)(x + (size_t)row * D);
    float4 v0 = xr[tid];
    float4 v1 = xr[tid + 256];
    float vals0[4] = {v0.x, v0.y, v0.z, v0.w};
    float vals1[4] = {v1.x, v1.y, v1.z, v1.w};

    float s = vals0[0] + vals0[1] + vals0[2] + vals0[3] + vals1[0] + vals1[1] + vals1[2] + vals1[3];
#pragma unroll
    for (int off = 32; off; off >>= 1) s += __shfl_xor(s, off);
    if ((tid & 63) == 0) red[tid >> 6] = s;
    __syncthreads();
    float mean = (red[0] + red[1] + red[2] + red[3]) * (1.0f / 2048.0f);
    __syncthreads();

    float q = 0.0f;
#pragma unroll
    for (int j = 0; j < 4; ++j) {
        float t0 = vals0[j] - mean;
        float t1 = vals1[j] - mean;
        q += t0 * t0 + t1 * t1;
    }
#pragma unroll
    for (int off = 32; off; off >>= 1) q += __shfl_xor(q, off);
    if ((tid & 63) == 0) red[tid >> 6] = q;
    __syncthreads();
    float var = (red[0] + red[1] + red[2] + red[3]) * (1.0f / 2048.0f);
    float inv = rsqrtf(var + 1e-5f);

    const int c0 = tid * 4;
    const int c1 = (tid + 256) * 4;
    short4v o0, o1;
#pragma unroll
    for (int j = 0; j < 4; ++j) {
        o0[j] = f2bs(sc[c0 + j] * ((vals0[j] - mean) * inv) + sh[c0 + j]);
        o1[j] = f2bs(sc[c1 + j] * ((vals1[j] - mean) * inv) + sh[c1 + j]);
    }
    *(short4v*)(out + (size_t)row * D + c0) = o0;
    *(short4v*)(out + (size_t)row * D + c1) = o1;
}

// ---------- bf16 GEMM (m97 structure): C[M,N] = A[M,K] @ Bt[N,K]^T ----------
// LDS linear [128][32] shorts, staged via global_load_lds w=16 with
// source-side XOR swizzle: slot' = slot ^ ((row>>1)&3). Reads swizzled back.
// EPI 0: bf16   EPI 1: fp32 = acc+bias+res   EPI 2: bf16 = gelu(acc+bias)
template <int EPI>
__global__ __launch_bounds__(256) void gemm_bf16(const short* __restrict__ A,
                                                 const short* __restrict__ Bt,
                                                 int M, int N, int K,
                                                 void* __restrict__ Cout,
                                                 const float* __restrict__ bias,
                                                 const float* __restrict__ res,
                                                 float gconst) {
    __shared__ __align__(16) short As[128 * 32];
    __shared__ __align__(16) short Bs[128 * 32];
    const int tid = threadIdx.x;
    const int lane = tid & 63;
    const int wid = tid >> 6;
    const int wm = wid >> 1, wn = wid & 1;
    const int l15 = lane & 15, grp = lane >> 4;
    const long m0 = (long)blockIdx.y * 128, n0 = (long)blockIdx.x * 128;

    // staging chunks: chunk c (16B): row=c>>2, slot=c&3; src slot' = slot^((row>>1)&3)
    const int ca = tid, cb2 = tid + 256;
    const int ra_ = ca >> 2, sa_ = (ca & 3) ^ ((ra_ >> 1) & 3);
    const int rb_ = cb2 >> 2, sb_ = (cb2 & 3) ^ ((rb_ >> 1) & 3);
    const short* gA0 = A + (m0 + ra_) * K + sa_ * 8;
    const short* gA1 = A + (m0 + rb_) * K + sb_ * 8;
    const short* gB0 = Bt + (n0 + ra_) * K + sa_ * 8;
    const short* gB1 = Bt + (n0 + rb_) * K + sb_ * 8;
    short* lA0 = As + (size_t)(wid * 64) * 8;
    short* lA1 = As + (size_t)(wid * 64 + 256) * 8;
    short* lB0 = Bs + (size_t)(wid * 64) * 8;
    short* lB1 = Bs + (size_t)(wid * 64 + 256) * 8;

    f32x4 zero = {0.f, 0.f, 0.f, 0.f};
    f32x4 acc[4][4];
#pragma unroll
    for (int i = 0; i < 4; i++)
#pragma unroll
        for (int j = 0; j < 4; j++) acc[i][j] = zero;

    // fragment read offsets (shorts): row*32 + (grp ^ ((row>>1)&3))*8
    int aoff[4], boff[4];
#pragma unroll
    for (int m = 0; m < 4; m++) {
        int rowa = wm * 64 + m * 16 + l15;
        aoff[m] = rowa * 32 + ((grp ^ ((rowa >> 1) & 3)) * 8);
        int rowb = wn * 64 + m * 16 + l15;
        boff[m] = rowb * 32 + ((grp ^ ((rowb >> 1) & 3)) * 8);
    }

    for (int k0 = 0; k0 < K; k0 += 32) {
        __syncthreads();
        gload_lds16(gA0 + k0, lA0);
        gload_lds16(gA1 + k0, lA1);
        gload_lds16(gB0 + k0, lB0);
        gload_lds16(gB1 + k0, lB1);
        __syncthreads();
        bf16x8 af[4], bfr[4];
#pragma unroll
        for (int m = 0; m < 4; m++) af[m] = *(const bf16x8*)(As + aoff[m]);
#pragma unroll
        for (int n = 0; n < 4; n++) bfr[n] = *(const bf16x8*)(Bs + boff[n]);
#pragma unroll
        for (int m = 0; m < 4; m++)
#pragma unroll
            for (int n = 0; n < 4; n++)
                acc[m][n] = MFMA16x32(af[m], bfr[n], acc[m][n]);
    }

#pragma unroll
    for (int m = 0; m < 4; m++) {
        long gr = m0 + wm * 64 + m * 16 + grp * 4;
#pragma unroll
        for (int n = 0; n < 4; n++) {
            long gcol = n0 + wn * 64 + n * 16 + l15;
#pragma unroll
            for (int r = 0; r < 4; r++) {
                float vv = acc[m][n][r];
                long idx = (gr + r) * N + gcol;
                if (EPI == 0) {
                    ((short*)Cout)[idx] = f2bs(vv);
                } else if (EPI == 1) {
                    ((float*)Cout)[idx] = vv + bias[gcol] + res[idx];
                } else {
                    float t = vv + bias[gcol];
                    float g = 0.5f * t * (1.0f + gconst * (t + 0.044715f * t * t * t));
                    ((short*)Cout)[idx] = f2bs(g);
                }
            }
        }
    }
}

// ---------- reshape: qkv[4096,6144] K-cols -> Kh[32][2048][128] ----------
__global__ __launch_bounds__(256) void reshape_k_kernel(const short* __restrict__ qkv,
                                                        short* __restrict__ Kh) {
    size_t idx = ((size_t)blockIdx.x * 256 + threadIdx.x) * 8;
    int d = (int)(idx & 127);
    int s = (int)((idx >> 7) & 2047);
    int bh = (int)(idx >> 18);
    int b = bh >> 4, h = bh & 15;
    const short* src = qkv + (size_t)(b * 2048 + s) * 6144 + 2048 + h * 128 + d;
    *(bf16x8*)(Kh + idx) = *(const bf16x8*)src;
}

// ---------- reshape: qkv V-cols -> Vt[32][128][2048] (transposed) ----------
__global__ __launch_bounds__(256) void reshape_v_kernel(const short* __restrict__ qkv,
                                                        short* __restrict__ Vt) {
    __shared__ short tile[32][33];
    const int bid = blockIdx.x;
    const int dt = bid & 3, st = (bid >> 2) & 63, bh = bid >> 8;
    const int b = bh >> 4, h = bh & 15;
    const int s0 = st * 32, d0 = dt * 32;
    const int tx = threadIdx.x & 31, ty = threadIdx.x >> 5;
#pragma unroll
    for (int i = 0; i < 4; ++i) {
        int s = ty + i * 8;
        tile[s][tx] = qkv[(size_t)(b * 2048 + s0 + s) * 6144 + 4096 + h * 128 + d0 + tx];
    }
    __syncthreads();
#pragma unroll
    for (int i = 0; i < 4; ++i) {
        int d = ty + i * 8;
        Vt[((size_t)bh * 128 + d0 + d) * 2048 + s0 + tx] = tile[tx][d];
    }
}

// ---------- causal flash attention: 4 waves x 16 q-rows, KVBLK=64 ----------
__global__ __launch_bounds__(256) void flash2_kernel(const short* __restrict__ qp,  // qkv, ld 6144
                                                     const short* __restrict__ Kh,  // [32][2048][128]
                                                     const short* __restrict__ Vt,  // [32][128][2048]
                                                     short* __restrict__ ctx) {
    const int S = 2048, D = 2048, HD = 128, LD = 6144;
    __shared__ __align__(16) short Ks[64 * 128];   // [64 k][128 d], src-swizzled
    __shared__ __align__(16) short Vs[128 * 64];   // [128 d][64 k], src-swizzled
    __shared__ __align__(16) short Ps[4][16 * 64]; // per-wave P, swizzled
    const int tid = threadIdx.x;
    const int lane = tid & 63, wid = tid >> 6;
    const int l15 = lane & 15, grp = lane >> 4;
    const int bid = blockIdx.x;
    const int qt = 31 - (bid & 31);   // heavy tiles first
    const int h = (bid >> 5) & 15;
    const int b = bid >> 9;
    const int bh = b * 16 + h;
    const int q0 = qt * 64;
    const int qw = q0 + wid * 16;
    const float scale = 0.08838834764831845f;
    const float NEGINF = -__builtin_inff();

    bf16x8 aq[4];
    const short* qrow = qp + (size_t)(b * S + qw + l15) * LD + h * HD;
#pragma unroll
    for (int kc = 0; kc < 4; kc++) aq[kc] = *(const bf16x8*)(qrow + kc * 32 + grp * 8);

    float m_[4], l_[4];
    f32x4 o[8];
    f32x4 zero = {0.f, 0.f, 0.f, 0.f};
#pragma unroll
    for (int r = 0; r < 4; r++) { m_[r] = NEGINF; l_[r] = 0.f; }
#pragma unroll
    for (int n = 0; n < 8; n++) o[n] = zero;

    const short* Kbase = Kh + (size_t)bh * S * 128;
    const short* Vbase = Vt + (size_t)bh * 128 * S;
    short* Psw = &Ps[wid][0];

    for (int kt = 0; kt <= qt; ++kt) {
        const int k0 = kt * 64;
        const bool lastTile = (kt == qt);
        __syncthreads();
        // stage K tile: 1024 chunks; chunk c: r=c>>4, sl=c&15; src sl^(r&7)
        const short* Kg = Kbase + (size_t)k0 * 128;
        const short* Vg = Vbase + k0;
#pragma unroll
        for (int j = 0; j < 4; ++j) {
            int c = tid + j * 256;
            int r = c >> 4, sl = c & 15;
            gload_lds16(Kg + (size_t)r * 128 + ((sl ^ (r & 7)) * 8),
                        Ks + (size_t)(wid * 64 + j * 256) * 8);
        }
        // stage V tile: chunk c: d=c>>3, sl=c&7; src sl^(d&7)
#pragma unroll
        for (int j = 0; j < 4; ++j) {
            int c = tid + j * 256;
            int d = c >> 3, sl = c & 7;
            gload_lds16(Vg + (size_t)d * S + ((sl ^ (d & 7)) * 8),
                        Vs + (size_t)(wid * 64 + j * 256) * 8);
        }
        __syncthreads();

        // QK^T
        f32x4 s[4] = {zero, zero, zero, zero};
#pragma unroll
        for (int n = 0; n < 4; ++n) {
            int r = n * 16 + l15;  // k-row in tile
#pragma unroll
            for (int kc = 0; kc < 4; ++kc) {
                bf16x8 kb = *(const bf16x8*)(Ks + r * 128 + (((kc * 4 + grp) ^ (r & 7)) * 8));
                s[n] = MFMA16x32(aq[kc], kb, s[n]);
            }
        }

        // online softmax + P write
        float al[4];
#pragma unroll
        for (int r = 0; r < 4; ++r) {
            float v[4];
#pragma unroll
            for (int n = 0; n < 4; ++n) v[n] = s[n][r] * scale;
            if (lastTile) {
                int qrel = wid * 16 + grp * 4 + r;
#pragma unroll
                for (int n = 0; n < 4; ++n)
                    if (n * 16 + l15 > qrel) v[n] = NEGINF;
            }
            float mx = fmaxf(fmaxf(v[0], v[1]), fmaxf(v[2], v[3]));
            mx = fmaxf(mx, __shfl_xor(mx, 1));
            mx = fmaxf(mx, __shfl_xor(mx, 2));
            mx = fmaxf(mx, __shfl_xor(mx, 4));
            mx = fmaxf(mx, __shfl_xor(mx, 8));
            float mn = fmaxf(m_[r], mx);
            float sc_ = __expf(m_[r] - mn);
            float rs = 0.f;
            int q = grp * 4 + r;
#pragma unroll
            for (int n = 0; n < 4; ++n) {
                v[n] = __expf(v[n] - mn);
                rs += v[n];
                // P[q][k=n*16+l15], swizzled: shorts = q*64 + ((n*2+(l15>>3))^(q&7))*8 + (l15&7)
                Psw[q * 64 + (((n * 2 + (l15 >> 3)) ^ (q & 7)) * 8) + (l15 & 7)] = f2bs(v[n]);
            }
            rs += __shfl_xor(rs, 1);
            rs += __shfl_xor(rs, 2);
            rs += __shfl_xor(rs, 4);
            rs += __shfl_xor(rs, 8);
            l_[r] = l_[r] * sc_ + rs;
            m_[r] = mn;
            al[r] = sc_;
        }
#pragma unroll
        for (int n = 0; n < 8; n++) {
            f32x4 t = o[n];
            t[0] *= al[0]; t[1] *= al[1]; t[2] *= al[2]; t[3] *= al[3];
            o[n] = t;
        }

        // PV: A = P frags, B = V^T frags
        bf16x8 pa[2];
#pragma unroll
        for (int kc = 0; kc < 2; ++kc)
            pa[kc] = *(const bf16x8*)(Psw + l15 * 64 + (((kc * 4 + grp) ^ (l15 & 7)) * 8));
#pragma unroll
        for (int n = 0; n < 8; ++n) {
            int d = n * 16 + l15;
#pragma unroll
            for (int kc = 0; kc < 2; ++kc) {
                bf16x8 vb = *(const bf16x8*)(Vs + d * 64 + (((kc * 4 + grp) ^ (d & 7)) * 8));
                o[n] = MFMA16x32(pa[kc], vb, o[n]);
            }
        }
    }

    float inv[4];
#pragma unroll
    for (int r = 0; r < 4; ++r) inv[r] = 1.0f / l_[r];
    short* cb_ = ctx + (size_t)(b * S + qw + grp * 4) * D + h * HD + l15;
#pragma unroll
    for (int n = 0; n < 8; ++n)
#pragma unroll
        for (int r = 0; r < 4; ++r)
            cb_[(size_t)r * D + n * 16] = f2bs(o[n][r] * inv[r]);
}

// ---------------------------------------------------------------------------
extern "C" void kernel_launch(void* const* d_in, const int* in_sizes, int n_in,
                              void* d_out, int out_size, void* d_ws, size_t ws_size,
                              hipStream_t stream) {
    const float* x    = (const float*)d_in[0];
    const float* wq   = (const float*)d_in[1];
    const float* wk   = (const float*)d_in[2];
    const float* wv   = (const float*)d_in[3];
    const float* wo   = (const float*)d_in[4];
    const float* bo   = (const float*)d_in[5];
    const float* w1   = (const float*)d_in[6];
    const float* b1   = (const float*)d_in[7];
    const float* w2   = (const float*)d_in[8];
    const float* b2   = (const float*)d_in[9];
    const float* lnsc = (const float*)d_in[10];
    const float* lnsh = (const float*)d_in[11];

    const int B = 2, S = 2048, D = 2048;
    const int M = B * S;  // 4096

    char* p = (char*)d_ws;
    short* wqkvT = (short*)p; p += (size_t)3 * D * D * 2;   // dead after qkv gemm
    short* woT   = (short*)p; p += (size_t)D * D * 2;
    short* w1T   = (short*)p; p += (size_t)4 * D * D * 2;
    short* w2T   = (short*)p; p += (size_t)4 * D * D * 2;
    short* lnb   = (short*)p; p += (size_t)M * D * 2;
    short* qkvb  = (short*)p;
    short* h1    = qkvb;                                    // reuse qkv+ctx span
    p += (size_t)M * 3 * D * 2;
    short* ctxb  = (short*)p; p += (size_t)M * D * 2;
    float* x2    = (float*)p; p += (size_t)M * D * 4;

    short* Kh = wqkvT;          // overlays wqkvT (dead after qkv gemm): 16.8MB <= 25.2MB
    short* Vt = (short*)x2;     // overlays x2 (written only by proj, after flash)

    const float gconst = tanhf(sqrtf(2.0f / 3.14159265358979323846f));

    dim3 blk(256);
    transpose_kernel<<<dim3(64, 64), blk, 0, stream>>>(wq, wqkvT, D, D);
    transpose_kernel<<<dim3(64, 64), blk, 0, stream>>>(wk, wqkvT + (size_t)D * D, D, D);
    transpose_kernel<<<dim3(64, 64), blk, 0, stream>>>(wv, wqkvT + (size_t)2 * D * D, D, D);
    transpose_kernel<<<dim3(64, 64), blk, 0, stream>>>(wo, woT, D, D);
    transpose_kernel<<<dim3(256, 64), blk, 0, stream>>>(w1, w1T, D, 4 * D);
    transpose_kernel<<<dim3(64, 256), blk, 0, stream>>>(w2, w2T, 4 * D, D);

    ln_kernel<<<dim3(M), blk, 0, stream>>>(x, lnsc, lnsh, lnb);
    gemm_bf16<0><<<dim3(3 * D / 128, M / 128), blk, 0, stream>>>(
        lnb, wqkvT, M, 3 * D, D, qkvb, nullptr, nullptr, 0.f);

    reshape_k_kernel<<<dim3(4096), blk, 0, stream>>>(qkvb, Kh);
    reshape_v_kernel<<<dim3(8192), blk, 0, stream>>>(qkvb, Vt);

    flash2_kernel<<<dim3(1024), blk, 0, stream>>>(qkvb, Kh, Vt, ctxb);

    gemm_bf16<1><<<dim3(D / 128, M / 128), blk, 0, stream>>>(
        ctxb, woT, M, D, D, x2, bo, x, 0.f);
    ln_kernel<<<dim3(M), blk, 0, stream>>>(x2, lnsc, lnsh, lnb);
    gemm_bf16<2><<<dim3(4 * D / 128, M / 128), blk, 0, stream>>>(
        lnb, w1T, M, 4 * D, D, h1, b1, nullptr, gconst);
    gemm_bf16<1><<<dim3(D / 128, M / 128), blk, 0, stream>>>(
        h1, w2T, M, D, 4 * D, (float*)d_out, b2, x2, 0.f);
}

// Round 3
// 796.050 us; speedup vs baseline: 1.2491x; 1.1803x over previous
//
#include <hip/hip_runtime.h>
#include <hip/hip_bf16.h>
#include <math.h>

// ---------------------------------------------------------------------------
// TransformerBlock fwd: ln1 -> qkv gemm -> causal flash attn -> proj+res
//   -> ln2 -> ffn1(buggy-gelu) -> ffn2+res.  bf16 MFMA, fp32 softmax/LN.
// R3: flash = paired q-tiles (perfect balance, 512 blocks) + double-buffered
//     K/V staging; T1 XCD swizzle on flash + GEMM grids.
// ---------------------------------------------------------------------------

typedef short bf16x8 __attribute__((ext_vector_type(8)));
typedef float f32x4 __attribute__((ext_vector_type(4)));
typedef short short4v __attribute__((ext_vector_type(4)));

#define MFMA16x32(a, b, c) __builtin_amdgcn_mfma_f32_16x16x32_bf16((a), (b), (c), 0, 0, 0)

__device__ __forceinline__ short f2bs(float f) {
    unsigned u = __builtin_bit_cast(unsigned, f);
    unsigned r = (u + 0x7FFFu + ((u >> 16) & 1u)) >> 16;
    return (short)(unsigned short)r;
}

__device__ __forceinline__ void gload_lds16(const void* g, void* l) {
    __builtin_amdgcn_global_load_lds(
        (const __attribute__((address_space(1))) unsigned int*)g,
        (__attribute__((address_space(3))) unsigned int*)l, 16, 0, 0);
}

// ---------- transpose fp32 (R x C) -> bf16 (C x R) ----------
__global__ __launch_bounds__(256) void transpose_kernel(const float* __restrict__ in,
                                                        short* __restrict__ out,
                                                        int R, int C) {
    __shared__ float tile[32][33];
    const int tx = threadIdx.x & 31;
    const int ty = threadIdx.x >> 5;
    const int c0 = blockIdx.x * 32;
    const int r0 = blockIdx.y * 32;
#pragma unroll
    for (int i = 0; i < 4; ++i) {
        int r = ty + i * 8;
        tile[r][tx] = in[(size_t)(r0 + r) * C + c0 + tx];
    }
    __syncthreads();
#pragma unroll
    for (int i = 0; i < 4; ++i) {
        int r = ty + i * 8;
        out[(size_t)(c0 + r) * R + r0 + tx] = f2bs(tile[tx][r]);
    }
}

// ---------- layernorm fp32 row (D=2048) -> bf16 row ----------
__global__ __launch_bounds__(256) void ln_kernel(const float* __restrict__ x,
                                                 const float* __restrict__ sc,
                                                 const float* __restrict__ sh,
                                                 short* __restrict__ out) {
    const int D = 2048;
    const int row = blockIdx.x;
    const int tid = threadIdx.x;
    __shared__ float red[4];
    const float4* xr = (const float4*)(x + (size_t)row * D);
    float4 v0 = xr[tid];
    float4 v1 = xr[tid + 256];
    float vals0[4] = {v0.x, v0.y, v0.z, v0.w};
    float vals1[4] = {v1.x, v1.y, v1.z, v1.w};

    float s = vals0[0] + vals0[1] + vals0[2] + vals0[3] + vals1[0] + vals1[1] + vals1[2] + vals1[3];
#pragma unroll
    for (int off = 32; off; off >>= 1) s += __shfl_xor(s, off);
    if ((tid & 63) == 0) red[tid >> 6] = s;
    __syncthreads();
    float mean = (red[0] + red[1] + red[2] + red[3]) * (1.0f / 2048.0f);
    __syncthreads();

    float q = 0.0f;
#pragma unroll
    for (int j = 0; j < 4; ++j) {
        float t0 = vals0[j] - mean;
        float t1 = vals1[j] - mean;
        q += t0 * t0 + t1 * t1;
    }
#pragma unroll
    for (int off = 32; off; off >>= 1) q += __shfl_xor(q, off);
    if ((tid & 63) == 0) red[tid >> 6] = q;
    __syncthreads();
    float var = (red[0] + red[1] + red[2] + red[3]) * (1.0f / 2048.0f);
    float inv = rsqrtf(var + 1e-5f);

    const int c0 = tid * 4;
    const int c1 = (tid + 256) * 4;
    short4v o0, o1;
#pragma unroll
    for (int j = 0; j < 4; ++j) {
        o0[j] = f2bs(sc[c0 + j] * ((vals0[j] - mean) * inv) + sh[c0 + j]);
        o1[j] = f2bs(sc[c1 + j] * ((vals1[j] - mean) * inv) + sh[c1 + j]);
    }
    *(short4v*)(out + (size_t)row * D + c0) = o0;
    *(short4v*)(out + (size_t)row * D + c1) = o1;
}

// ---------- bf16 GEMM (m97 structure): C[M,N] = A[M,K] @ Bt[N,K]^T ----------
template <int EPI>
__global__ __launch_bounds__(256) void gemm_bf16(const short* __restrict__ A,
                                                 const short* __restrict__ Bt,
                                                 int M, int N, int K,
                                                 void* __restrict__ Cout,
                                                 const float* __restrict__ bias,
                                                 const float* __restrict__ res,
                                                 float gconst) {
    __shared__ __align__(16) short As[128 * 32];
    __shared__ __align__(16) short Bs[128 * 32];
    const int tid = threadIdx.x;
    const int lane = tid & 63;
    const int wid = tid >> 6;
    const int wm = wid >> 1, wn = wid & 1;
    const int l15 = lane & 15, grp = lane >> 4;

    // T1 XCD-bijective remap (nwg % 8 == 0 for all launches here)
    const int gx = gridDim.x;
    int flat = (int)blockIdx.y * gx + (int)blockIdx.x;
    const int cpx = (gx * (int)gridDim.y) >> 3;
    flat = (flat & 7) * cpx + (flat >> 3);
    const int bx = flat % gx, by = flat / gx;
    const long m0 = (long)by * 128, n0 = (long)bx * 128;

    const int ca = tid, cb2 = tid + 256;
    const int ra_ = ca >> 2, sa_ = (ca & 3) ^ ((ra_ >> 1) & 3);
    const int rb_ = cb2 >> 2, sb_ = (cb2 & 3) ^ ((rb_ >> 1) & 3);
    const short* gA0 = A + (m0 + ra_) * K + sa_ * 8;
    const short* gA1 = A + (m0 + rb_) * K + sb_ * 8;
    const short* gB0 = Bt + (n0 + ra_) * K + sa_ * 8;
    const short* gB1 = Bt + (n0 + rb_) * K + sb_ * 8;
    short* lA0 = As + (size_t)(wid * 64) * 8;
    short* lA1 = As + (size_t)(wid * 64 + 256) * 8;
    short* lB0 = Bs + (size_t)(wid * 64) * 8;
    short* lB1 = Bs + (size_t)(wid * 64 + 256) * 8;

    f32x4 zero = {0.f, 0.f, 0.f, 0.f};
    f32x4 acc[4][4];
#pragma unroll
    for (int i = 0; i < 4; i++)
#pragma unroll
        for (int j = 0; j < 4; j++) acc[i][j] = zero;

    int aoff[4], boff[4];
#pragma unroll
    for (int m = 0; m < 4; m++) {
        int rowa = wm * 64 + m * 16 + l15;
        aoff[m] = rowa * 32 + ((grp ^ ((rowa >> 1) & 3)) * 8);
        int rowb = wn * 64 + m * 16 + l15;
        boff[m] = rowb * 32 + ((grp ^ ((rowb >> 1) & 3)) * 8);
    }

    for (int k0 = 0; k0 < K; k0 += 32) {
        __syncthreads();
        gload_lds16(gA0 + k0, lA0);
        gload_lds16(gA1 + k0, lA1);
        gload_lds16(gB0 + k0, lB0);
        gload_lds16(gB1 + k0, lB1);
        __syncthreads();
        bf16x8 af[4], bfr[4];
#pragma unroll
        for (int m = 0; m < 4; m++) af[m] = *(const bf16x8*)(As + aoff[m]);
#pragma unroll
        for (int n = 0; n < 4; n++) bfr[n] = *(const bf16x8*)(Bs + boff[n]);
#pragma unroll
        for (int m = 0; m < 4; m++)
#pragma unroll
            for (int n = 0; n < 4; n++)
                acc[m][n] = MFMA16x32(af[m], bfr[n], acc[m][n]);
    }

#pragma unroll
    for (int m = 0; m < 4; m++) {
        long gr = m0 + wm * 64 + m * 16 + grp * 4;
#pragma unroll
        for (int n = 0; n < 4; n++) {
            long gcol = n0 + wn * 64 + n * 16 + l15;
#pragma unroll
            for (int r = 0; r < 4; r++) {
                float vv = acc[m][n][r];
                long idx = (gr + r) * N + gcol;
                if (EPI == 0) {
                    ((short*)Cout)[idx] = f2bs(vv);
                } else if (EPI == 1) {
                    ((float*)Cout)[idx] = vv + bias[gcol] + res[idx];
                } else {
                    float t = vv + bias[gcol];
                    float g = 0.5f * t * (1.0f + gconst * (t + 0.044715f * t * t * t));
                    ((short*)Cout)[idx] = f2bs(g);
                }
            }
        }
    }
}

// ---------- reshape: qkv[4096,6144] K-cols -> Kh[32][2048][128] ----------
__global__ __launch_bounds__(256) void reshape_k_kernel(const short* __restrict__ qkv,
                                                        short* __restrict__ Kh) {
    size_t idx = ((size_t)blockIdx.x * 256 + threadIdx.x) * 8;
    int d = (int)(idx & 127);
    int s = (int)((idx >> 7) & 2047);
    int bh = (int)(idx >> 18);
    int b = bh >> 4, h = bh & 15;
    const short* src = qkv + (size_t)(b * 2048 + s) * 6144 + 2048 + h * 128 + d;
    *(bf16x8*)(Kh + idx) = *(const bf16x8*)src;
}

// ---------- reshape: qkv V-cols -> Vt[32][128][2048] (transposed) ----------
__global__ __launch_bounds__(256) void reshape_v_kernel(const short* __restrict__ qkv,
                                                        short* __restrict__ Vt) {
    __shared__ short tile[32][33];
    const int bid = blockIdx.x;
    const int dt = bid & 3, st = (bid >> 2) & 63, bh = bid >> 8;
    const int b = bh >> 4, h = bh & 15;
    const int s0 = st * 32, d0 = dt * 32;
    const int tx = threadIdx.x & 31, ty = threadIdx.x >> 5;
#pragma unroll
    for (int i = 0; i < 4; ++i) {
        int s = ty + i * 8;
        tile[s][tx] = qkv[(size_t)(b * 2048 + s0 + s) * 6144 + 4096 + h * 128 + d0 + tx];
    }
    __syncthreads();
#pragma unroll
    for (int i = 0; i < 4; ++i) {
        int d = ty + i * 8;
        Vt[((size_t)bh * 128 + d0 + d) * 2048 + s0 + tx] = tile[tx][d];
    }
}

// ---------- causal flash attention, paired q-tiles + double-buffered K/V ----
// grid 512: block handles q-tiles (31-p) then (p) for one bh -> 33 k-tiles each.
__global__ __launch_bounds__(256) void flash3_kernel(const short* __restrict__ qp,  // qkv, ld 6144
                                                     const short* __restrict__ Kh,  // [32][2048][128]
                                                     const short* __restrict__ Vt,  // [32][128][2048]
                                                     short* __restrict__ ctx) {
    const int S = 2048, D = 2048, HD = 128, LD = 6144;
    __shared__ __align__(16) short Ks[2][64 * 128];
    __shared__ __align__(16) short Vs[2][64 * 128];
    __shared__ __align__(16) short Ps[4][16 * 64];
    const int tid = threadIdx.x;
    const int lane = tid & 63, wid = tid >> 6;
    const int l15 = lane & 15, grp = lane >> 4;

    // T1: group each bh's 16 pair-blocks onto one XCD (nwg=512, chunk=64)
    int bid = (int)blockIdx.x;
    bid = (bid & 7) * 64 + (bid >> 3);
    const int p = bid & 15, bh = bid >> 4;
    const int b = bh >> 4, h = bh & 15;
    const int qtH = 31 - p;
    const int nH = qtH + 1;  // 17..32
    const float scale = 0.08838834764831845f;
    const float NEGINF = -__builtin_inff();

    const short* Kbase = Kh + (size_t)bh * S * 128;
    const short* Vbase = Vt + (size_t)bh * 128 * S;
    short* Psw = &Ps[wid][0];

    f32x4 zero = {0.f, 0.f, 0.f, 0.f};
    bf16x8 aq[4];
    float m_[4], l_[4];
    f32x4 o[8];

    int qt = qtH;
    int qw = qt * 64 + wid * 16;
    {
        const short* qrow = qp + (size_t)(b * S + qw + l15) * LD + h * HD;
#pragma unroll
        for (int kc = 0; kc < 4; kc++) aq[kc] = *(const bf16x8*)(qrow + kc * 32 + grp * 8);
    }
#pragma unroll
    for (int r = 0; r < 4; r++) { m_[r] = NEGINF; l_[r] = 0.f; }
#pragma unroll
    for (int n = 0; n < 8; n++) o[n] = zero;

    // initial stage: tile 0 -> buf 0
#pragma unroll
    for (int j = 0; j < 4; ++j) {
        int c = tid + j * 256;
        int r = c >> 4, sl = c & 15;
        gload_lds16(Kbase + (size_t)r * 128 + ((sl ^ (r & 7)) * 8),
                    Ks[0] + (size_t)(wid * 64 + j * 256) * 8);
    }
#pragma unroll
    for (int j = 0; j < 4; ++j) {
        int c = tid + j * 256;
        int d = c >> 3, sl = c & 7;
        gload_lds16(Vbase + (size_t)d * S + ((sl ^ (d & 7)) * 8),
                    Vs[0] + (size_t)(wid * 64 + j * 256) * 8);
    }
    __syncthreads();

    int cur = 0;
    for (int i = 0; i < 33; ++i) {
        const int kt = (i < nH) ? i : (i - nH);
        const bool lastT = (kt == qt);

        // prefetch next tile into cur^1 (loads in flight during compute)
        if (i + 1 < 33) {
            const int ktn = (i + 1 < nH) ? (i + 1) : (i + 1 - nH);
            const long kn0 = (long)ktn * 64;
            const short* Kg = Kbase + kn0 * 128;
            const short* Vg = Vbase + kn0;
            short* kd = Ks[cur ^ 1];
            short* vd = Vs[cur ^ 1];
#pragma unroll
            for (int j = 0; j < 4; ++j) {
                int c = tid + j * 256;
                int r = c >> 4, sl = c & 15;
                gload_lds16(Kg + (size_t)r * 128 + ((sl ^ (r & 7)) * 8),
                            kd + (size_t)(wid * 64 + j * 256) * 8);
            }
#pragma unroll
            for (int j = 0; j < 4; ++j) {
                int c = tid + j * 256;
                int d = c >> 3, sl = c & 7;
                gload_lds16(Vg + (size_t)d * S + ((sl ^ (d & 7)) * 8),
                            vd + (size_t)(wid * 64 + j * 256) * 8);
            }
        }

        const short* Kc = Ks[cur];
        const short* Vc = Vs[cur];

        // QK^T
        f32x4 s[4] = {zero, zero, zero, zero};
#pragma unroll
        for (int n = 0; n < 4; ++n) {
            int r = n * 16 + l15;
#pragma unroll
            for (int kc = 0; kc < 4; ++kc) {
                bf16x8 kb = *(const bf16x8*)(Kc + r * 128 + (((kc * 4 + grp) ^ (r & 7)) * 8));
                s[n] = MFMA16x32(aq[kc], kb, s[n]);
            }
        }

        // online softmax + P write
        float al[4];
#pragma unroll
        for (int r = 0; r < 4; ++r) {
            float v[4];
#pragma unroll
            for (int n = 0; n < 4; ++n) v[n] = s[n][r] * scale;
            if (lastT) {
                int qrel = wid * 16 + grp * 4 + r;
#pragma unroll
                for (int n = 0; n < 4; ++n)
                    if (n * 16 + l15 > qrel) v[n] = NEGINF;
            }
            float mx = fmaxf(fmaxf(v[0], v[1]), fmaxf(v[2], v[3]));
            mx = fmaxf(mx, __shfl_xor(mx, 1));
            mx = fmaxf(mx, __shfl_xor(mx, 2));
            mx = fmaxf(mx, __shfl_xor(mx, 4));
            mx = fmaxf(mx, __shfl_xor(mx, 8));
            float mn = fmaxf(m_[r], mx);
            float sc_ = __expf(m_[r] - mn);
            float rs = 0.f;
            int q = grp * 4 + r;
#pragma unroll
            for (int n = 0; n < 4; ++n) {
                v[n] = __expf(v[n] - mn);
                rs += v[n];
                Psw[q * 64 + (((n * 2 + (l15 >> 3)) ^ (q & 7)) * 8) + (l15 & 7)] = f2bs(v[n]);
            }
            rs += __shfl_xor(rs, 1);
            rs += __shfl_xor(rs, 2);
            rs += __shfl_xor(rs, 4);
            rs += __shfl_xor(rs, 8);
            l_[r] = l_[r] * sc_ + rs;
            m_[r] = mn;
            al[r] = sc_;
        }
#pragma unroll
        for (int n = 0; n < 8; n++) {
            f32x4 t = o[n];
            t[0] *= al[0]; t[1] *= al[1]; t[2] *= al[2]; t[3] *= al[3];
            o[n] = t;
        }

        // PV
        bf16x8 pa[2];
#pragma unroll
        for (int kc = 0; kc < 2; ++kc)
            pa[kc] = *(const bf16x8*)(Psw + l15 * 64 + (((kc * 4 + grp) ^ (l15 & 7)) * 8));
#pragma unroll
        for (int n = 0; n < 8; ++n) {
            int d = n * 16 + l15;
#pragma unroll
            for (int kc = 0; kc < 2; ++kc) {
                bf16x8 vb = *(const bf16x8*)(Vc + d * 64 + (((kc * 4 + grp) ^ (d & 7)) * 8));
                o[n] = MFMA16x32(pa[kc], vb, o[n]);
            }
        }

        // end of phase: write O, then reset for the light q-tile
        if (lastT) {
            float inv[4];
#pragma unroll
            for (int r = 0; r < 4; ++r) inv[r] = 1.0f / l_[r];
            short* cb_ = ctx + (size_t)(b * S + qw + grp * 4) * D + h * HD + l15;
#pragma unroll
            for (int n = 0; n < 8; ++n)
#pragma unroll
                for (int r = 0; r < 4; ++r)
                    cb_[(size_t)r * D + n * 16] = f2bs(o[n][r] * inv[r]);
            if (i < 32) {
                qt = 31 - qtH;  // = p
                qw = qt * 64 + wid * 16;
                const short* qrow = qp + (size_t)(b * S + qw + l15) * LD + h * HD;
#pragma unroll
                for (int kc = 0; kc < 4; kc++) aq[kc] = *(const bf16x8*)(qrow + kc * 32 + grp * 8);
#pragma unroll
                for (int r = 0; r < 4; r++) { m_[r] = NEGINF; l_[r] = 0.f; }
#pragma unroll
                for (int n = 0; n < 8; n++) o[n] = zero;
            }
        }
        __syncthreads();  // all waves done with buf cur; prefetch into cur^1 drained
        cur ^= 1;
    }
}

// ---------------------------------------------------------------------------
extern "C" void kernel_launch(void* const* d_in, const int* in_sizes, int n_in,
                              void* d_out, int out_size, void* d_ws, size_t ws_size,
                              hipStream_t stream) {
    const float* x    = (const float*)d_in[0];
    const float* wq   = (const float*)d_in[1];
    const float* wk   = (const float*)d_in[2];
    const float* wv   = (const float*)d_in[3];
    const float* wo   = (const float*)d_in[4];
    const float* bo   = (const float*)d_in[5];
    const float* w1   = (const float*)d_in[6];
    const float* b1   = (const float*)d_in[7];
    const float* w2   = (const float*)d_in[8];
    const float* b2   = (const float*)d_in[9];
    const float* lnsc = (const float*)d_in[10];
    const float* lnsh = (const float*)d_in[11];

    const int B = 2, S = 2048, D = 2048;
    const int M = B * S;  // 4096

    char* p = (char*)d_ws;
    short* wqkvT = (short*)p; p += (size_t)3 * D * D * 2;   // dead after qkv gemm
    short* woT   = (short*)p; p += (size_t)D * D * 2;
    short* w1T   = (short*)p; p += (size_t)4 * D * D * 2;
    short* w2T   = (short*)p; p += (size_t)4 * D * D * 2;
    short* lnb   = (short*)p; p += (size_t)M * D * 2;
    short* qkvb  = (short*)p;
    short* h1    = qkvb;                                    // reuse qkv+ctx span
    p += (size_t)M * 3 * D * 2;
    short* ctxb  = (short*)p; p += (size_t)M * D * 2;
    float* x2    = (float*)p; p += (size_t)M * D * 4;

    short* Kh = wqkvT;          // overlays wqkvT (dead after qkv gemm)
    short* Vt = (short*)x2;     // overlays x2 (written only by proj, after flash)

    const float gconst = tanhf(sqrtf(2.0f / 3.14159265358979323846f));

    dim3 blk(256);
    transpose_kernel<<<dim3(64, 64), blk, 0, stream>>>(wq, wqkvT, D, D);
    transpose_kernel<<<dim3(64, 64), blk, 0, stream>>>(wk, wqkvT + (size_t)D * D, D, D);
    transpose_kernel<<<dim3(64, 64), blk, 0, stream>>>(wv, wqkvT + (size_t)2 * D * D, D, D);
    transpose_kernel<<<dim3(64, 64), blk, 0, stream>>>(wo, woT, D, D);
    transpose_kernel<<<dim3(256, 64), blk, 0, stream>>>(w1, w1T, D, 4 * D);
    transpose_kernel<<<dim3(64, 256), blk, 0, stream>>>(w2, w2T, 4 * D, D);

    ln_kernel<<<dim3(M), blk, 0, stream>>>(x, lnsc, lnsh, lnb);
    gemm_bf16<0><<<dim3(3 * D / 128, M / 128), blk, 0, stream>>>(
        lnb, wqkvT, M, 3 * D, D, qkvb, nullptr, nullptr, 0.f);

    reshape_k_kernel<<<dim3(4096), blk, 0, stream>>>(qkvb, Kh);
    reshape_v_kernel<<<dim3(8192), blk, 0, stream>>>(qkvb, Vt);

    flash3_kernel<<<dim3(512), blk, 0, stream>>>(qkvb, Kh, Vt, ctxb);

    gemm_bf16<1><<<dim3(D / 128, M / 128), blk, 0, stream>>>(
        ctxb, woT, M, D, D, x2, bo, x, 0.f);
    ln_kernel<<<dim3(M), blk, 0, stream>>>(x2, lnsc, lnsh, lnb);
    gemm_bf16<2><<<dim3(4 * D / 128, M / 128), blk, 0, stream>>>(
        lnb, w1T, M, 4 * D, D, h1, b1, nullptr, gconst);
    gemm_bf16<1><<<dim3(D / 128, M / 128), blk, 0, stream>>>(
        h1, w2T, M, D, 4 * D, (float*)d_out, b2, x2, 0.f);
}

// Round 4
// 655.138 us; speedup vs baseline: 1.5178x; 1.2151x over previous
//
#include <hip/hip_runtime.h>
#include <hip/hip_bf16.h>
#include <math.h>

// ---------------------------------------------------------------------------
// TransformerBlock fwd: ln1 -> qkv gemm -> causal flash attn -> proj+res
//   -> ln2 -> ffn1(buggy-gelu) -> ffn2+res.  bf16 MFMA, fp32 softmax/LN.
// R4: GEMM -> counted-vmcnt pipelined template (T3+T4+T5):
//     BM=256,BN=128,BK=64, 512 thr, triple-buffered LDS (144KB dynamic),
//     stage(t+2) + s_waitcnt vmcnt(12) (never 0 in loop), raw s_barrier,
//     full 3-bit T2 swizzle. Flash/LN/transpose unchanged from R3.
// ---------------------------------------------------------------------------

typedef short bf16x8 __attribute__((ext_vector_type(8)));
typedef float f32x4 __attribute__((ext_vector_type(4)));
typedef short short4v __attribute__((ext_vector_type(4)));

#define MFMA16x32(a, b, c) __builtin_amdgcn_mfma_f32_16x16x32_bf16((a), (b), (c), 0, 0, 0)

__device__ __forceinline__ short f2bs(float f) {
    unsigned u = __builtin_bit_cast(unsigned, f);
    unsigned r = (u + 0x7FFFu + ((u >> 16) & 1u)) >> 16;
    return (short)(unsigned short)r;
}

__device__ __forceinline__ void gload_lds16(const void* g, void* l) {
    __builtin_amdgcn_global_load_lds(
        (const __attribute__((address_space(1))) unsigned int*)g,
        (__attribute__((address_space(3))) unsigned int*)l, 16, 0, 0);
}

// ---------- transpose fp32 (R x C) -> bf16 (C x R) ----------
__global__ __launch_bounds__(256) void transpose_kernel(const float* __restrict__ in,
                                                        short* __restrict__ out,
                                                        int R, int C) {
    __shared__ float tile[32][33];
    const int tx = threadIdx.x & 31;
    const int ty = threadIdx.x >> 5;
    const int c0 = blockIdx.x * 32;
    const int r0 = blockIdx.y * 32;
#pragma unroll
    for (int i = 0; i < 4; ++i) {
        int r = ty + i * 8;
        tile[r][tx] = in[(size_t)(r0 + r) * C + c0 + tx];
    }
    __syncthreads();
#pragma unroll
    for (int i = 0; i < 4; ++i) {
        int r = ty + i * 8;
        out[(size_t)(c0 + r) * R + r0 + tx] = f2bs(tile[tx][r]);
    }
}

// ---------- layernorm fp32 row (D=2048) -> bf16 row ----------
__global__ __launch_bounds__(256) void ln_kernel(const float* __restrict__ x,
                                                 const float* __restrict__ sc,
                                                 const float* __restrict__ sh,
                                                 short* __restrict__ out) {
    const int D = 2048;
    const int row = blockIdx.x;
    const int tid = threadIdx.x;
    __shared__ float red[4];
    const float4* xr = (const float4*)(x + (size_t)row * D);
    float4 v0 = xr[tid];
    float4 v1 = xr[tid + 256];
    float vals0[4] = {v0.x, v0.y, v0.z, v0.w};
    float vals1[4] = {v1.x, v1.y, v1.z, v1.w};

    float s = vals0[0] + vals0[1] + vals0[2] + vals0[3] + vals1[0] + vals1[1] + vals1[2] + vals1[3];
#pragma unroll
    for (int off = 32; off; off >>= 1) s += __shfl_xor(s, off);
    if ((tid & 63) == 0) red[tid >> 6] = s;
    __syncthreads();
    float mean = (red[0] + red[1] + red[2] + red[3]) * (1.0f / 2048.0f);
    __syncthreads();

    float q = 0.0f;
#pragma unroll
    for (int j = 0; j < 4; ++j) {
        float t0 = vals0[j] - mean;
        float t1 = vals1[j] - mean;
        q += t0 * t0 + t1 * t1;
    }
#pragma unroll
    for (int off = 32; off; off >>= 1) q += __shfl_xor(q, off);
    if ((tid & 63) == 0) red[tid >> 6] = q;
    __syncthreads();
    float var = (red[0] + red[1] + red[2] + red[3]) * (1.0f / 2048.0f);
    float inv = rsqrtf(var + 1e-5f);

    const int c0 = tid * 4;
    const int c1 = (tid + 256) * 4;
    short4v o0, o1;
#pragma unroll
    for (int j = 0; j < 4; ++j) {
        o0[j] = f2bs(sc[c0 + j] * ((vals0[j] - mean) * inv) + sh[c0 + j]);
        o1[j] = f2bs(sc[c1 + j] * ((vals1[j] - mean) * inv) + sh[c1 + j]);
    }
    *(short4v*)(out + (size_t)row * D + c0) = o0;
    *(short4v*)(out + (size_t)row * D + c1) = o1;
}

// ---------- bf16 GEMM, counted-vmcnt pipeline ----------
// C[M,N] = A[M,K] @ Bt[N,K]^T.  BM=256 BN=128 BK=64, 512 thr (8 waves 4Mx2N).
// LDS: 3 buffers x (A 256x64 + B 128x64) bf16 = 144KB dynamic.
// Swizzle (T2): LDS(row, p) holds global k-chunk p^(row&7); reads invert.
// EPI 0: bf16   EPI 1: fp32 = acc+bias+res   EPI 2: bf16 = gelu(acc+bias)
template <int EPI>
__global__ __launch_bounds__(512, 1) void gemm_bf16(const short* __restrict__ A,
                                                    const short* __restrict__ Bt,
                                                    int M, int N, int K,
                                                    void* __restrict__ Cout,
                                                    const float* __restrict__ bias,
                                                    const float* __restrict__ res,
                                                    float gconst) {
    extern __shared__ __align__(16) short lds[];  // 3 * 24576 shorts
    const int tid = threadIdx.x;
    const int lane = tid & 63;
    const int wid = tid >> 6;          // 0..7
    const int wm = wid >> 1, wn = wid & 1;
    const int l15 = lane & 15, grp = lane >> 4;

    // T1 XCD-bijective remap (grid size % 8 == 0 for all launches here)
    const int gx = gridDim.x;
    int flat = (int)blockIdx.y * gx + (int)blockIdx.x;
    const int cpx = (gx * (int)gridDim.y) >> 3;
    flat = (flat & 7) * cpx + (flat >> 3);
    const int bx = flat % gx, by = flat / gx;
    const long m0 = (long)by * 256, n0 = (long)bx * 128;

    f32x4 zero = {0.f, 0.f, 0.f, 0.f};
    f32x4 acc[4][4];
#pragma unroll
    for (int i = 0; i < 4; i++)
#pragma unroll
        for (int j = 0; j < 4; j++) acc[i][j] = zero;

    // stage one K-tile (BK=64) into buffer b: A 2048 chunks, B 1024 chunks
    auto STAGE = [&](long k0, int b) {
        short* bufA = lds + b * 24576;
        short* bufB = bufA + 16384;
#pragma unroll
        for (int j = 0; j < 4; ++j) {
            int c = tid + j * 512;
            int row = c >> 3, sl = (c & 7) ^ (row & 7);
            gload_lds16(A + (size_t)(m0 + row) * K + k0 + sl * 8,
                        bufA + (size_t)(wid * 64 + j * 512) * 8);
        }
#pragma unroll
        for (int j = 0; j < 2; ++j) {
            int c = tid + j * 512;
            int row = c >> 3, sl = (c & 7) ^ (row & 7);
            gload_lds16(Bt + (size_t)(n0 + row) * K + k0 + sl * 8,
                        bufB + (size_t)(wid * 64 + j * 512) * 8);
        }
    };

    const int nt = K >> 6;
    STAGE(0, 0);
    STAGE(64, 1);
    int cur = 0, nx2 = 2;

    for (int t = 0; t < nt; ++t) {
        if (t + 2 < nt) {
            STAGE((long)(t + 2) * 64, nx2);
            asm volatile("s_waitcnt vmcnt(12)" ::: "memory");
        } else if (t + 1 < nt) {
            asm volatile("s_waitcnt vmcnt(6)" ::: "memory");
        } else {
            asm volatile("s_waitcnt vmcnt(0)" ::: "memory");
        }
        __builtin_amdgcn_s_barrier();
        __builtin_amdgcn_sched_barrier(0);

        const short* bufA = lds + cur * 24576;
        const short* bufB = bufA + 16384;
        bf16x8 af[2][4], bfr[2][4];
#pragma unroll
        for (int kk = 0; kk < 2; ++kk) {
#pragma unroll
            for (int m = 0; m < 4; ++m) {
                int row = wm * 64 + m * 16 + l15;
                af[kk][m] = *(const bf16x8*)(bufA + row * 64 + (((kk * 4 + grp) ^ (row & 7)) * 8));
            }
#pragma unroll
            for (int n = 0; n < 4; ++n) {
                int row = wn * 64 + n * 16 + l15;
                bfr[kk][n] = *(const bf16x8*)(bufB + row * 64 + (((kk * 4 + grp) ^ (row & 7)) * 8));
            }
        }
        __builtin_amdgcn_s_setprio(1);
#pragma unroll
        for (int kk = 0; kk < 2; ++kk)
#pragma unroll
            for (int m = 0; m < 4; ++m)
#pragma unroll
                for (int n = 0; n < 4; ++n)
                    acc[m][n] = MFMA16x32(af[kk][m], bfr[kk][n], acc[m][n]);
        __builtin_amdgcn_s_setprio(0);
        asm volatile("s_waitcnt lgkmcnt(0)" ::: "memory");
        __builtin_amdgcn_s_barrier();
        __builtin_amdgcn_sched_barrier(0);
        cur = (cur == 2) ? 0 : cur + 1;
        nx2 = (nx2 == 2) ? 0 : nx2 + 1;
    }

#pragma unroll
    for (int m = 0; m < 4; m++) {
        long gr = m0 + wm * 64 + m * 16 + grp * 4;
#pragma unroll
        for (int n = 0; n < 4; n++) {
            long gcol = n0 + wn * 64 + n * 16 + l15;
#pragma unroll
            for (int r = 0; r < 4; r++) {
                float vv = acc[m][n][r];
                long idx = (gr + r) * N + gcol;
                if (EPI == 0) {
                    ((short*)Cout)[idx] = f2bs(vv);
                } else if (EPI == 1) {
                    ((float*)Cout)[idx] = vv + bias[gcol] + res[idx];
                } else {
                    float t = vv + bias[gcol];
                    float g = 0.5f * t * (1.0f + gconst * (t + 0.044715f * t * t * t));
                    ((short*)Cout)[idx] = f2bs(g);
                }
            }
        }
    }
}

// ---------- reshape: qkv[4096,6144] K-cols -> Kh[32][2048][128] ----------
__global__ __launch_bounds__(256) void reshape_k_kernel(const short* __restrict__ qkv,
                                                        short* __restrict__ Kh) {
    size_t idx = ((size_t)blockIdx.x * 256 + threadIdx.x) * 8;
    int d = (int)(idx & 127);
    int s = (int)((idx >> 7) & 2047);
    int bh = (int)(idx >> 18);
    int b = bh >> 4, h = bh & 15;
    const short* src = qkv + (size_t)(b * 2048 + s) * 6144 + 2048 + h * 128 + d;
    *(bf16x8*)(Kh + idx) = *(const bf16x8*)src;
}

// ---------- reshape: qkv V-cols -> Vt[32][128][2048] (transposed) ----------
__global__ __launch_bounds__(256) void reshape_v_kernel(const short* __restrict__ qkv,
                                                        short* __restrict__ Vt) {
    __shared__ short tile[32][33];
    const int bid = blockIdx.x;
    const int dt = bid & 3, st = (bid >> 2) & 63, bh = bid >> 8;
    const int b = bh >> 4, h = bh & 15;
    const int s0 = st * 32, d0 = dt * 32;
    const int tx = threadIdx.x & 31, ty = threadIdx.x >> 5;
#pragma unroll
    for (int i = 0; i < 4; ++i) {
        int s = ty + i * 8;
        tile[s][tx] = qkv[(size_t)(b * 2048 + s0 + s) * 6144 + 4096 + h * 128 + d0 + tx];
    }
    __syncthreads();
#pragma unroll
    for (int i = 0; i < 4; ++i) {
        int d = ty + i * 8;
        Vt[((size_t)bh * 128 + d0 + d) * 2048 + s0 + tx] = tile[tx][d];
    }
}

// ---------- causal flash attention, paired q-tiles + double-buffered K/V ----
__global__ __launch_bounds__(256) void flash3_kernel(const short* __restrict__ qp,  // qkv, ld 6144
                                                     const short* __restrict__ Kh,  // [32][2048][128]
                                                     const short* __restrict__ Vt,  // [32][128][2048]
                                                     short* __restrict__ ctx) {
    const int S = 2048, D = 2048, HD = 128, LD = 6144;
    __shared__ __align__(16) short Ks[2][64 * 128];
    __shared__ __align__(16) short Vs[2][64 * 128];
    __shared__ __align__(16) short Ps[4][16 * 64];
    const int tid = threadIdx.x;
    const int lane = tid & 63, wid = tid >> 6;
    const int l15 = lane & 15, grp = lane >> 4;

    int bid = (int)blockIdx.x;
    bid = (bid & 7) * 64 + (bid >> 3);
    const int p = bid & 15, bh = bid >> 4;
    const int b = bh >> 4, h = bh & 15;
    const int qtH = 31 - p;
    const int nH = qtH + 1;
    const float scale = 0.08838834764831845f;
    const float NEGINF = -__builtin_inff();

    const short* Kbase = Kh + (size_t)bh * S * 128;
    const short* Vbase = Vt + (size_t)bh * 128 * S;
    short* Psw = &Ps[wid][0];

    f32x4 zero = {0.f, 0.f, 0.f, 0.f};
    bf16x8 aq[4];
    float m_[4], l_[4];
    f32x4 o[8];

    int qt = qtH;
    int qw = qt * 64 + wid * 16;
    {
        const short* qrow = qp + (size_t)(b * S + qw + l15) * LD + h * HD;
#pragma unroll
        for (int kc = 0; kc < 4; kc++) aq[kc] = *(const bf16x8*)(qrow + kc * 32 + grp * 8);
    }
#pragma unroll
    for (int r = 0; r < 4; r++) { m_[r] = NEGINF; l_[r] = 0.f; }
#pragma unroll
    for (int n = 0; n < 8; n++) o[n] = zero;

#pragma unroll
    for (int j = 0; j < 4; ++j) {
        int c = tid + j * 256;
        int r = c >> 4, sl = c & 15;
        gload_lds16(Kbase + (size_t)r * 128 + ((sl ^ (r & 7)) * 8),
                    Ks[0] + (size_t)(wid * 64 + j * 256) * 8);
    }
#pragma unroll
    for (int j = 0; j < 4; ++j) {
        int c = tid + j * 256;
        int d = c >> 3, sl = c & 7;
        gload_lds16(Vbase + (size_t)d * S + ((sl ^ (d & 7)) * 8),
                    Vs[0] + (size_t)(wid * 64 + j * 256) * 8);
    }
    __syncthreads();

    int cur = 0;
    for (int i = 0; i < 33; ++i) {
        const int kt = (i < nH) ? i : (i - nH);
        const bool lastT = (kt == qt);

        if (i + 1 < 33) {
            const int ktn = (i + 1 < nH) ? (i + 1) : (i + 1 - nH);
            const long kn0 = (long)ktn * 64;
            const short* Kg = Kbase + kn0 * 128;
            const short* Vg = Vbase + kn0;
            short* kd = Ks[cur ^ 1];
            short* vd = Vs[cur ^ 1];
#pragma unroll
            for (int j = 0; j < 4; ++j) {
                int c = tid + j * 256;
                int r = c >> 4, sl = c & 15;
                gload_lds16(Kg + (size_t)r * 128 + ((sl ^ (r & 7)) * 8),
                            kd + (size_t)(wid * 64 + j * 256) * 8);
            }
#pragma unroll
            for (int j = 0; j < 4; ++j) {
                int c = tid + j * 256;
                int d = c >> 3, sl = c & 7;
                gload_lds16(Vg + (size_t)d * S + ((sl ^ (d & 7)) * 8),
                            vd + (size_t)(wid * 64 + j * 256) * 8);
            }
        }

        const short* Kc = Ks[cur];
        const short* Vc = Vs[cur];

        f32x4 s[4] = {zero, zero, zero, zero};
#pragma unroll
        for (int n = 0; n < 4; ++n) {
            int r = n * 16 + l15;
#pragma unroll
            for (int kc = 0; kc < 4; ++kc) {
                bf16x8 kb = *(const bf16x8*)(Kc + r * 128 + (((kc * 4 + grp) ^ (r & 7)) * 8));
                s[n] = MFMA16x32(aq[kc], kb, s[n]);
            }
        }

        float al[4];
#pragma unroll
        for (int r = 0; r < 4; ++r) {
            float v[4];
#pragma unroll
            for (int n = 0; n < 4; ++n) v[n] = s[n][r] * scale;
            if (lastT) {
                int qrel = wid * 16 + grp * 4 + r;
#pragma unroll
                for (int n = 0; n < 4; ++n)
                    if (n * 16 + l15 > qrel) v[n] = NEGINF;
            }
            float mx = fmaxf(fmaxf(v[0], v[1]), fmaxf(v[2], v[3]));
            mx = fmaxf(mx, __shfl_xor(mx, 1));
            mx = fmaxf(mx, __shfl_xor(mx, 2));
            mx = fmaxf(mx, __shfl_xor(mx, 4));
            mx = fmaxf(mx, __shfl_xor(mx, 8));
            float mn = fmaxf(m_[r], mx);
            float sc_ = __expf(m_[r] - mn);
            float rs = 0.f;
            int q = grp * 4 + r;
#pragma unroll
            for (int n = 0; n < 4; ++n) {
                v[n] = __expf(v[n] - mn);
                rs += v[n];
                Psw[q * 64 + (((n * 2 + (l15 >> 3)) ^ (q & 7)) * 8) + (l15 & 7)] = f2bs(v[n]);
            }
            rs += __shfl_xor(rs, 1);
            rs += __shfl_xor(rs, 2);
            rs += __shfl_xor(rs, 4);
            rs += __shfl_xor(rs, 8);
            l_[r] = l_[r] * sc_ + rs;
            m_[r] = mn;
            al[r] = sc_;
        }
#pragma unroll
        for (int n = 0; n < 8; n++) {
            f32x4 t = o[n];
            t[0] *= al[0]; t[1] *= al[1]; t[2] *= al[2]; t[3] *= al[3];
            o[n] = t;
        }

        bf16x8 pa[2];
#pragma unroll
        for (int kc = 0; kc < 2; ++kc)
            pa[kc] = *(const bf16x8*)(Psw + l15 * 64 + (((kc * 4 + grp) ^ (l15 & 7)) * 8));
#pragma unroll
        for (int n = 0; n < 8; ++n) {
            int d = n * 16 + l15;
#pragma unroll
            for (int kc = 0; kc < 2; ++kc) {
                bf16x8 vb = *(const bf16x8*)(Vc + d * 64 + (((kc * 4 + grp) ^ (d & 7)) * 8));
                o[n] = MFMA16x32(pa[kc], vb, o[n]);
            }
        }

        if (lastT) {
            float inv[4];
#pragma unroll
            for (int r = 0; r < 4; ++r) inv[r] = 1.0f / l_[r];
            short* cb_ = ctx + (size_t)(b * S + qw + grp * 4) * D + h * HD + l15;
#pragma unroll
            for (int n = 0; n < 8; ++n)
#pragma unroll
                for (int r = 0; r < 4; ++r)
                    cb_[(size_t)r * D + n * 16] = f2bs(o[n][r] * inv[r]);
            if (i < 32) {
                qt = 31 - qtH;
                qw = qt * 64 + wid * 16;
                const short* qrow = qp + (size_t)(b * S + qw + l15) * LD + h * HD;
#pragma unroll
                for (int kc = 0; kc < 4; kc++) aq[kc] = *(const bf16x8*)(qrow + kc * 32 + grp * 8);
#pragma unroll
                for (int r = 0; r < 4; r++) { m_[r] = NEGINF; l_[r] = 0.f; }
#pragma unroll
                for (int n = 0; n < 8; n++) o[n] = zero;
            }
        }
        __syncthreads();
        cur ^= 1;
    }
}

// ---------------------------------------------------------------------------
extern "C" void kernel_launch(void* const* d_in, const int* in_sizes, int n_in,
                              void* d_out, int out_size, void* d_ws, size_t ws_size,
                              hipStream_t stream) {
    const float* x    = (const float*)d_in[0];
    const float* wq   = (const float*)d_in[1];
    const float* wk   = (const float*)d_in[2];
    const float* wv   = (const float*)d_in[3];
    const float* wo   = (const float*)d_in[4];
    const float* bo   = (const float*)d_in[5];
    const float* w1   = (const float*)d_in[6];
    const float* b1   = (const float*)d_in[7];
    const float* w2   = (const float*)d_in[8];
    const float* b2   = (const float*)d_in[9];
    const float* lnsc = (const float*)d_in[10];
    const float* lnsh = (const float*)d_in[11];

    const int B = 2, S = 2048, D = 2048;
    const int M = B * S;  // 4096
    const int GEMM_LDS = 3 * 24576 * 2;  // 144 KB

    char* p = (char*)d_ws;
    short* wqkvT = (short*)p; p += (size_t)3 * D * D * 2;   // dead after qkv gemm
    short* woT   = (short*)p; p += (size_t)D * D * 2;
    short* w1T   = (short*)p; p += (size_t)4 * D * D * 2;
    short* w2T   = (short*)p; p += (size_t)4 * D * D * 2;
    short* lnb   = (short*)p; p += (size_t)M * D * 2;
    short* qkvb  = (short*)p;
    short* h1    = qkvb;                                    // reuse qkv+ctx span
    p += (size_t)M * 3 * D * 2;
    short* ctxb  = (short*)p; p += (size_t)M * D * 2;
    float* x2    = (float*)p; p += (size_t)M * D * 4;

    short* Kh = wqkvT;          // overlays wqkvT (dead after qkv gemm)
    short* Vt = (short*)x2;     // overlays x2 (written only by proj, after flash)

    const float gconst = tanhf(sqrtf(2.0f / 3.14159265358979323846f));

    // allow 144KB dynamic LDS (idempotent; not a stream op)
    hipFuncSetAttribute((const void*)&gemm_bf16<0>, hipFuncAttributeMaxDynamicSharedMemorySize, GEMM_LDS);
    hipFuncSetAttribute((const void*)&gemm_bf16<1>, hipFuncAttributeMaxDynamicSharedMemorySize, GEMM_LDS);
    hipFuncSetAttribute((const void*)&gemm_bf16<2>, hipFuncAttributeMaxDynamicSharedMemorySize, GEMM_LDS);

    dim3 blk(256);
    transpose_kernel<<<dim3(64, 64), blk, 0, stream>>>(wq, wqkvT, D, D);
    transpose_kernel<<<dim3(64, 64), blk, 0, stream>>>(wk, wqkvT + (size_t)D * D, D, D);
    transpose_kernel<<<dim3(64, 64), blk, 0, stream>>>(wv, wqkvT + (size_t)2 * D * D, D, D);
    transpose_kernel<<<dim3(64, 64), blk, 0, stream>>>(wo, woT, D, D);
    transpose_kernel<<<dim3(256, 64), blk, 0, stream>>>(w1, w1T, D, 4 * D);
    transpose_kernel<<<dim3(64, 256), blk, 0, stream>>>(w2, w2T, 4 * D, D);

    ln_kernel<<<dim3(M), blk, 0, stream>>>(x, lnsc, lnsh, lnb);
    // qkv: [4096,2048]@[2048,6144] -> grid 48x16
    gemm_bf16<0><<<dim3(3 * D / 128, M / 256), dim3(512), GEMM_LDS, stream>>>(
        lnb, wqkvT, M, 3 * D, D, qkvb, nullptr, nullptr, 0.f);

    reshape_k_kernel<<<dim3(4096), blk, 0, stream>>>(qkvb, Kh);
    reshape_v_kernel<<<dim3(8192), blk, 0, stream>>>(qkvb, Vt);

    flash3_kernel<<<dim3(512), blk, 0, stream>>>(qkvb, Kh, Vt, ctxb);

    // proj: grid 16x16
    gemm_bf16<1><<<dim3(D / 128, M / 256), dim3(512), GEMM_LDS, stream>>>(
        ctxb, woT, M, D, D, x2, bo, x, 0.f);
    ln_kernel<<<dim3(M), blk, 0, stream>>>(x2, lnsc, lnsh, lnb);
    // ffn1: grid 64x16
    gemm_bf16<2><<<dim3(4 * D / 128, M / 256), dim3(512), GEMM_LDS, stream>>>(
        lnb, w1T, M, 4 * D, D, h1, b1, nullptr, gconst);
    // ffn2: grid 16x16
    gemm_bf16<1><<<dim3(D / 128, M / 256), dim3(512), GEMM_LDS, stream>>>(
        h1, w2T, M, D, 4 * D, (float*)d_out, b2, x2, 0.f);
}